// Round 6
// baseline (196.253 us; speedup 1.0000x reference)
//
#include <hip/hip_runtime.h>
#include <stdint.h>

#define B_ 16
#define N_ 4096
#define R_ 256

typedef short bf16x8 __attribute__((ext_vector_type(8)));
typedef float f32x4 __attribute__((ext_vector_type(4)));
typedef uint32_t u32;

// V[b,n,i] = (n==i) ? 1 : (n>i ? param[b,n,i] : 0)
// Pipeline: S = V^T V (split-bf16 MFMA, 3 upper 128x128 tiles, 16 n-chunk
// partials filling d_out) -> reduce (in-place into chunk 0 => S = d_out base)
// -> solve (diag(1/tau)+strictU(S)) W = Vtop^T (wave-per-column, block-shared
// LDS S-panels, W packed hi|lo bf16 into d_ws) -> Q = E - V W (MFMA).
//
// Split: fp32 x ~= hi + lo, both TRUNCATED bf16 (5 VALU ops; lo = x - hi is
// exact, trunc err ~2^-16|x|). x*y ~= xh*yh + xh*yl + xl*yh (3 MFMAs).

__device__ __forceinline__ u32 pack_split(float x) {
  u32 u = __float_as_uint(x);
  u32 h = u & 0xffff0000u;           // hi = trunc bf16
  float l = x - __uint_as_float(h);  // exact remainder
  return h | (__float_as_uint(l) >> 16);
}

// Build hi/lo bf16x8 fragments from 8 packed words (k-order preserved).
__device__ __forceinline__ void unpack8(const u32* w, bf16x8& hi, bf16x8& lo) {
  union { u32 u[4]; bf16x8 v; } H, L;
#pragma unroll
  for (int i = 0; i < 4; ++i) {
    u32 a = w[2 * i], b = w[2 * i + 1];
    H.u[i] = (a >> 16) | (b & 0xffff0000u);
    L.u[i] = (a & 0xffffu) | (b << 16);
  }
  hi = H.v; lo = L.v;
}

// Read one A/B fragment pair from a swizzled [row][32-word] LDS tile.
__device__ __forceinline__ void read_frag(const u32* rowbase, int row, int q2,
                                          bf16x8& hi, bf16x8& lo) {
  u32 w[8];
  const int s = row & 7;
  *(uint4*)&w[0] = *(const uint4*)(rowbase + (((q2    ) ^ s) << 2));
  *(uint4*)&w[4] = *(const uint4*)(rowbase + (((q2 + 1) ^ s) << 2));
  unpack8(w, hi, lo);
}

__device__ __forceinline__ f32x4 mm3(bf16x8 ah, bf16x8 al, bf16x8 bh, bf16x8 bl,
                                     f32x4 c) {
  c = __builtin_amdgcn_mfma_f32_16x16x32_bf16(al, bh, c, 0, 0, 0);
  c = __builtin_amdgcn_mfma_f32_16x16x32_bf16(ah, bl, c, 0, 0, 0);
  c = __builtin_amdgcn_mfma_f32_16x16x32_bf16(ah, bh, c, 0, 0, 0);
  return c;
}

// ---------------------------------------------------------------------------
// K1: partial Gram via MFMA. grid (3 tiles, 16 n-chunks of 256, 16 b), 256 thr.
// tile0=(0,0) tile1=(0,128) tile2=(128,128).
// T14 prefetch: next iter's global loads issued before the MFMA phase so HBM
// latency hides under compute. Writes SP[chunk][b][256][256] (3 tiles only).
// ---------------------------------------------------------------------------
__global__ __launch_bounds__(256) void gram_kernel(const float* __restrict__ param,
                                                   float* __restrict__ SP) {
  const int tile = blockIdx.x, chunk = blockIdx.y, b = blockIdx.z;
  const int j0 = (tile == 2) ? 128 : 0;
  const int k0 = (tile == 0) ? 0 : 128;
  const float* __restrict__ P = param + (size_t)b * N_ * R_;

  __shared__ u32 VT[256][32];

  const int t = threadIdx.x;
  const int lane = t & 63, wv = t >> 6;
  const int wr = wv >> 1, wc = wv & 1;
  const int l15 = lane & 15, q = lane >> 4;
  const int bbase = (tile == 1) ? 128 : 0;

  f32x4 acc[4][4];
#pragma unroll
  for (int i = 0; i < 4; ++i)
#pragma unroll
    for (int j = 0; j < 4; ++j) acc[i][j] = (f32x4){0.f, 0.f, 0.f, 0.f};

  const int nb = chunk * 256;
  const int ns = (nb > k0) ? nb : k0;  // n < k0: B cols all zero
  const int ne = nb + 256;

  // staging register file (tile1 uses 32, others 16)
  float ld[32];

  const int ct1 = t;                    // tile1 slot/col
  const int ct0 = t & 127;              // tile0/2 slot
  const int gc0 = j0 + ct0;
  const int hb  = t >> 7;

  auto do_load = [&](int n0) {
    if (tile == 1) {
#pragma unroll
      for (int ri = 0; ri < 8; ++ri)
#pragma unroll
        for (int s = 0; s < 4; ++s)
          ld[4 * ri + s] = P[(size_t)(n0 + 4 * ri + s) * R_ + ct1];
    } else {
#pragma unroll
      for (int ri = 0; ri < 4; ++ri)
#pragma unroll
        for (int s = 0; s < 4; ++s)
          ld[4 * ri + s] = P[(size_t)(n0 + 4 * (2 * ri + hb) + s) * R_ + gc0];
    }
  };

  auto do_write = [&](int n0) {
    if (tile == 1) {
#pragma unroll
      for (int ri = 0; ri < 8; ++ri) {
        u32 qw[4];
#pragma unroll
        for (int s = 0; s < 4; ++s) {
          int n = n0 + 4 * ri + s;
          float v = (n == ct1) ? 1.f : ((n > ct1) ? ld[4 * ri + s] : 0.f);
          qw[s] = pack_split(v);
        }
        *(uint4*)&VT[ct1][((ri ^ (ct1 & 7)) << 2)] = *(uint4*)qw;
      }
    } else {
#pragma unroll
      for (int ri = 0; ri < 4; ++ri) {
        int ch = 2 * ri + hb;
        u32 qw[4];
#pragma unroll
        for (int s = 0; s < 4; ++s) {
          int n = n0 + 4 * ch + s;
          float v = (n == gc0) ? 1.f : ((n > gc0) ? ld[4 * ri + s] : 0.f);
          qw[s] = pack_split(v);
        }
        *(uint4*)&VT[ct0][((ch ^ (ct0 & 7)) << 2)] = *(uint4*)qw;
      }
    }
  };

  do_load(ns);
  for (int n0 = ns; n0 < ne; n0 += 32) {
    do_write(n0);
    __syncthreads();
    if (n0 + 32 < ne) do_load(n0 + 32);  // prefetch: overlaps MFMA below

    bf16x8 Ah[4], Al[4];
#pragma unroll
    for (int mt = 0; mt < 4; ++mt) {
      int row = 64 * wr + 16 * mt + l15;
      read_frag(&VT[row][0], row, 2 * q, Ah[mt], Al[mt]);
    }
#pragma unroll
    for (int nt = 0; nt < 4; ++nt) {
      int brow = bbase + 64 * wc + 16 * nt + l15;
      bf16x8 bh, bl;
      read_frag(&VT[brow][0], brow, 2 * q, bh, bl);
#pragma unroll
      for (int mt = 0; mt < 4; ++mt)
        acc[mt][nt] = mm3(Ah[mt], Al[mt], bh, bl, acc[mt][nt]);
    }
    __syncthreads();
  }

  // C/D layout: col=lane&15, row=(lane>>4)*4+reg
  float* Sp = SP + (size_t)(chunk * 16 + b) * (R_ * R_);
#pragma unroll
  for (int mt = 0; mt < 4; ++mt)
#pragma unroll
    for (int nt = 0; nt < 4; ++nt) {
      int jj = j0 + 64 * wr + 16 * mt + 4 * q;
      int kk = k0 + 64 * wc + 16 * nt + l15;
#pragma unroll
      for (int r = 0; r < 4; ++r)
        Sp[(size_t)(jj + r) * R_ + kk] = acc[mt][nt][r];
    }
}

// ---------------------------------------------------------------------------
// reduce: S = sum over 16 chunks of SP, IN PLACE into chunk-0 slot.
// grid 1024, block 256 (one float4 each).
// ---------------------------------------------------------------------------
__global__ __launch_bounds__(256) void reduce_kernel(float* __restrict__ SP) {
  size_t idx = (size_t)blockIdx.x * 256 + threadIdx.x;  // float4 index
  float4* sp = (float4*)SP;
  float4 a = sp[idx];
#pragma unroll
  for (int c = 1; c < 16; ++c) {
    float4 v = sp[idx + (size_t)c * 262144];
    a.x += v.x; a.y += v.y; a.z += v.z; a.w += v.w;
  }
  sp[idx] = a;
}

// ---------------------------------------------------------------------------
// K2: wave-per-column backward substitution with block-cooperative LDS
// panels. Block = 4 waves = 4 consecutive columns kbase..kbase+3 -> all share
// the SAME k4 (kbase ≡ 0 mod 4), so every wave is active every iteration.
// Double-buffered 4-row S panel (4 KB) staged coalesced by all 256 threads;
// the global load for panel r4-1 is issued BEFORE the butterfly so its
// latency hides under ~250 cycles of compute. Math is bit-identical to R5.
// ---------------------------------------------------------------------------
__global__ __launch_bounds__(256) void solve_kernel(const float* __restrict__ param,
                                                    const float* __restrict__ S,
                                                    u32* __restrict__ WtP) {
  const int t    = threadIdx.x;
  const int lane = t & 63;
  const int gw   = blockIdx.x * 4 + (t >> 6);
  const int b    = gw >> 8;
  const int k    = gw & 255;
  const int k4   = k >> 2;              // uniform across the block
  const float* __restrict__ Sb = S + (size_t)b * R_ * R_;
  const float* __restrict__ Pb = param + (size_t)b * N_ * R_;

  __shared__ float panel[2][4][256];

  // rhs column: x[c] = (c==k)?1:(c<k ? param[b,k,c] : 0)
  float4 x = *(const float4*)(Pb + (size_t)k * R_ + 4 * lane);
  {
    int c0 = 4 * lane;
    x.x = (c0     == k) ? 1.f : ((c0     < k) ? x.x : 0.f);
    x.y = (c0 + 1 == k) ? 1.f : ((c0 + 1 < k) ? x.y : 0.f);
    x.z = (c0 + 2 == k) ? 1.f : ((c0 + 2 < k) ? x.z : 0.f);
    x.w = (c0 + 3 == k) ? 1.f : ((c0 + 3 < k) ? x.w : 0.f);
  }
  float4 w = make_float4(0.f, 0.f, 0.f, 0.f);

  const float4* Srow4 = (const float4*)Sb;  // row r: Srow4[r*64 + col4]
  const int srow = t >> 6;                  // 0..3  (panel row this thread stages)
  const int scol = t & 63;                  // float4 column

  // stage first panel (rows 4*k4 .. 4*k4+3)
  float4 g = Srow4[(size_t)(4 * k4 + srow) * 64 + scol];
  *(float4*)&panel[0][srow][4 * scol] = g;
  __syncthreads();

  for (int r4 = k4;; --r4) {
    const int  p    = (k4 - r4) & 1;
    const bool more = (r4 > 0);
    if (more) g = Srow4[(size_t)(4 * (r4 - 1) + srow) * 64 + scol];  // issue early

    float4 rA0 = *(const float4*)&panel[p][0][4 * lane];
    float4 rA1 = *(const float4*)&panel[p][1][4 * lane];
    float4 rA2 = *(const float4*)&panel[p][2][4 * lane];
    float4 rA3 = *(const float4*)&panel[p][3][4 * lane];

    float s0 = fmaf(rA0.x, w.x, fmaf(rA0.y, w.y, fmaf(rA0.z, w.z, rA0.w * w.w)));
    float s1 = fmaf(rA1.x, w.x, fmaf(rA1.y, w.y, fmaf(rA1.z, w.z, rA1.w * w.w)));
    float s2 = fmaf(rA2.x, w.x, fmaf(rA2.y, w.y, fmaf(rA2.z, w.z, rA2.w * w.w)));
    float s3 = fmaf(rA3.x, w.x, fmaf(rA3.y, w.y, fmaf(rA3.z, w.z, rA3.w * w.w)));
#pragma unroll
    for (int m = 1; m < 64; m <<= 1) {
      s0 += __shfl_xor(s0, m);
      s1 += __shfl_xor(s1, m);
      s2 += __shfl_xor(s2, m);
      s3 += __shfl_xor(s3, m);
    }
    // owner-lane correction chain (rows 4r4+3 .. 4r4); on lane r4 the rAj
    // float4 holds S[4r4+j][4r4..4r4+3] (the diagonal block columns).
    float w3 = 2.f * __builtin_amdgcn_rcpf(rA3.w) * (x.w - s3);
    float s2c = fmaf(rA2.w, w3, s2);
    float w2 = 2.f * __builtin_amdgcn_rcpf(rA2.z) * (x.z - s2c);
    float s1c = fmaf(rA1.z, w2, fmaf(rA1.w, w3, s1));
    float w1 = 2.f * __builtin_amdgcn_rcpf(rA1.y) * (x.y - s1c);
    float s0c = fmaf(rA0.y, w1, fmaf(rA0.z, w2, fmaf(rA0.w, w3, s0)));
    float w0 = 2.f * __builtin_amdgcn_rcpf(rA0.x) * (x.x - s0c);
    if (lane == r4) { w.w = w3; w.z = w2; w.y = w1; w.x = w0; }

    if (more) *(float4*)&panel[1 - p][srow][4 * scol] = g;  // vmcnt waited here
    __syncthreads();
    if (!more) break;
  }

  u32 pw[4] = { pack_split(w.x), pack_split(w.y), pack_split(w.z), pack_split(w.w) };
  *(uint4*)(WtP + ((size_t)b * R_ + k) * R_ + 4 * lane) = *(uint4*)pw;
}

// ---------------------------------------------------------------------------
// K3: Q = E - V @ W via MFMA. grid (32, 2, 16), block 256 (4 waves 2x2).
// 128x128 output tile, BK=32. LDS VA/WB XOR-swizzled packed u32.
// ---------------------------------------------------------------------------
__global__ __launch_bounds__(256) void final_kernel(const float* __restrict__ param,
                                                    const u32* __restrict__ WtP,
                                                    float* __restrict__ Q) {
  const int b  = blockIdx.z;
  const int n0 = blockIdx.x * 128;
  const int k0 = blockIdx.y * 128;
  const float* __restrict__ Pb = param + (size_t)b * N_ * R_;
  const u32* __restrict__ Wb = WtP + (size_t)b * R_ * R_;
  float* __restrict__ Qb = Q + (size_t)b * N_ * R_;

  __shared__ u32 VA[128][32];
  __shared__ u32 WB[128][32];

  const int t = threadIdx.x;
  const int lane = t & 63, wv = t >> 6;
  const int wr = wv >> 1, wc = wv & 1;
  const int l15 = lane & 15, q = lane >> 4;
  const int row8 = t >> 3;   // 0..31
  const int c4 = t & 7;

  f32x4 acc[4][4];
#pragma unroll
  for (int i = 0; i < 4; ++i)
#pragma unroll
    for (int j = 0; j < 4; ++j) acc[i][j] = (f32x4){0.f, 0.f, 0.f, 0.f};

  const int jend = k0 + 128;
  for (int jb = 0; jb < jend; jb += 32) {
#pragma unroll
    for (int pi = 0; pi < 4; ++pi) {
      int row = row8 + 32 * pi;
      int n = n0 + row;
      int gj = jb + 4 * c4;
      float4 v = *(const float4*)&Pb[(size_t)n * R_ + gj];
      u32 qw[4];
      qw[0] = pack_split((n == gj    ) ? 1.f : ((n > gj    ) ? v.x : 0.f));
      qw[1] = pack_split((n == gj + 1) ? 1.f : ((n > gj + 1) ? v.y : 0.f));
      qw[2] = pack_split((n == gj + 2) ? 1.f : ((n > gj + 2) ? v.z : 0.f));
      qw[3] = pack_split((n == gj + 3) ? 1.f : ((n > gj + 3) ? v.w : 0.f));
      *(uint4*)&VA[row][((c4 ^ (row & 7)) << 2)] = *(uint4*)qw;
      uint4 wq = *(const uint4*)&Wb[(size_t)(k0 + row) * R_ + gj];
      *(uint4*)&WB[row][((c4 ^ (row & 7)) << 2)] = wq;
    }
    __syncthreads();

    bf16x8 Ah[4], Al[4];
#pragma unroll
    for (int mt = 0; mt < 4; ++mt) {
      int row = 64 * wr + 16 * mt + l15;
      read_frag(&VA[row][0], row, 2 * q, Ah[mt], Al[mt]);
    }
#pragma unroll
    for (int nt = 0; nt < 4; ++nt) {
      int krow = 64 * wc + 16 * nt + l15;
      bf16x8 bh, bl;
      read_frag(&WB[krow][0], krow, 2 * q, bh, bl);
#pragma unroll
      for (int mt = 0; mt < 4; ++mt)
        acc[mt][nt] = mm3(Ah[mt], Al[mt], bh, bl, acc[mt][nt]);
    }
    __syncthreads();
  }

#pragma unroll
  for (int mt = 0; mt < 4; ++mt)
#pragma unroll
    for (int nt = 0; nt < 4; ++nt) {
      int nrow = n0 + 64 * wr + 16 * mt + 4 * q;
      int kcol = k0 + 64 * wc + 16 * nt + l15;
#pragma unroll
      for (int r = 0; r < 4; ++r) {
        float val = ((nrow + r == kcol) ? 1.f : 0.f) - acc[mt][nt][r];
        Qb[(size_t)(nrow + r) * R_ + kcol] = val;
      }
    }
}

extern "C" void kernel_launch(void* const* d_in, const int* in_sizes, int n_in,
                              void* d_out, int out_size, void* d_ws, size_t ws_size,
                              hipStream_t stream) {
  const float* param = (const float*)d_in[0];
  float* Q  = (float*)d_out;
  // d_out during pipeline: SP = 16 chunks x 16 b x 256x256 fp32 = the WHOLE
  // 64 MB of d_out. reduce sums chunks 1..15 into chunk 0 in place, so
  // S = d_out base. final_kernel then overwrites all of d_out with Q.
  float* SP = Q;
  float* S  = Q;
  u32*   WtP = (u32*)d_ws;  // 4 MB packed split-bf16 W^T

  gram_kernel<<<dim3(3, 16, B_), 256, 0, stream>>>(param, SP);
  reduce_kernel<<<dim3(1024), 256, 0, stream>>>(SP);
  solve_kernel<<<dim3(1024), 256, 0, stream>>>(param, S, WtP);
  final_kernel<<<dim3(32, 2, B_), 256, 0, stream>>>(param, WtP, Q);
}

// Round 7
// 166.781 us; speedup vs baseline: 1.1767x; 1.1767x over previous
//
#include <hip/hip_runtime.h>
#include <stdint.h>

#define B_ 16
#define N_ 4096
#define R_ 256

typedef short bf16x8 __attribute__((ext_vector_type(8)));
typedef float f32x4 __attribute__((ext_vector_type(4)));
typedef uint32_t u32;

// V[b,n,i] = (n==i) ? 1 : (n>i ? param[b,n,i] : 0)
// Pipeline: S = V^T V (split-bf16 MFMA, 3 upper 128x128 tiles, 16 n-chunk
// partials filling d_out) -> reduce (in-place into chunk 0 => S = d_out base)
// -> solve (diag(1/tau)+strictU(S)) W = Vtop^T (wave-per-column over an
// LDS-resident upper-triangular S, W packed hi|lo bf16 into d_ws)
// -> Q = E - V W (split-bf16 MFMA).
//
// Split: fp32 x ~= hi + lo, both TRUNCATED bf16 (5 VALU ops; lo = x - hi is
// exact, trunc err ~2^-16|x|). x*y ~= xh*yh + xh*yl + xl*yh (3 MFMAs).

__device__ __forceinline__ u32 pack_split(float x) {
  u32 u = __float_as_uint(x);
  u32 h = u & 0xffff0000u;           // hi = trunc bf16
  float l = x - __uint_as_float(h);  // exact remainder
  return h | (__float_as_uint(l) >> 16);
}

// Build hi/lo bf16x8 fragments from 8 packed words (k-order preserved).
__device__ __forceinline__ void unpack8(const u32* w, bf16x8& hi, bf16x8& lo) {
  union { u32 u[4]; bf16x8 v; } H, L;
#pragma unroll
  for (int i = 0; i < 4; ++i) {
    u32 a = w[2 * i], b = w[2 * i + 1];
    H.u[i] = (a >> 16) | (b & 0xffff0000u);
    L.u[i] = (a & 0xffffu) | (b << 16);
  }
  hi = H.v; lo = L.v;
}

// Read one A/B fragment pair from a swizzled [row][32-word] LDS tile.
__device__ __forceinline__ void read_frag(const u32* rowbase, int row, int q2,
                                          bf16x8& hi, bf16x8& lo) {
  u32 w[8];
  const int s = row & 7;
  *(uint4*)&w[0] = *(const uint4*)(rowbase + (((q2    ) ^ s) << 2));
  *(uint4*)&w[4] = *(const uint4*)(rowbase + (((q2 + 1) ^ s) << 2));
  unpack8(w, hi, lo);
}

__device__ __forceinline__ f32x4 mm3(bf16x8 ah, bf16x8 al, bf16x8 bh, bf16x8 bl,
                                     f32x4 c) {
  c = __builtin_amdgcn_mfma_f32_16x16x32_bf16(al, bh, c, 0, 0, 0);
  c = __builtin_amdgcn_mfma_f32_16x16x32_bf16(ah, bl, c, 0, 0, 0);
  c = __builtin_amdgcn_mfma_f32_16x16x32_bf16(ah, bh, c, 0, 0, 0);
  return c;
}

// ---------------------------------------------------------------------------
// K1: partial Gram via MFMA. grid (3 tiles, 16 n-chunks of 256, 16 b), 256 thr.
// tile0=(0,0) tile1=(0,128) tile2=(128,128).
// ---------------------------------------------------------------------------
__global__ __launch_bounds__(256) void gram_kernel(const float* __restrict__ param,
                                                   float* __restrict__ SP) {
  const int tile = blockIdx.x, chunk = blockIdx.y, b = blockIdx.z;
  const int j0 = (tile == 2) ? 128 : 0;
  const int k0 = (tile == 0) ? 0 : 128;
  const float* __restrict__ P = param + (size_t)b * N_ * R_;

  __shared__ u32 VT[256][32];

  const int t = threadIdx.x;
  const int lane = t & 63, wv = t >> 6;
  const int wr = wv >> 1, wc = wv & 1;
  const int l15 = lane & 15, q = lane >> 4;
  const int bbase = (tile == 1) ? 128 : 0;

  f32x4 acc[4][4];
#pragma unroll
  for (int i = 0; i < 4; ++i)
#pragma unroll
    for (int j = 0; j < 4; ++j) acc[i][j] = (f32x4){0.f, 0.f, 0.f, 0.f};

  const int nb = chunk * 256;
  const int ns = (nb > k0) ? nb : k0;  // n < k0: B cols all zero
  const int ne = nb + 256;

  float ld[32];

  const int ct1 = t;
  const int ct0 = t & 127;
  const int gc0 = j0 + ct0;
  const int hb  = t >> 7;

  auto do_load = [&](int n0) {
    if (tile == 1) {
#pragma unroll
      for (int ri = 0; ri < 8; ++ri)
#pragma unroll
        for (int s = 0; s < 4; ++s)
          ld[4 * ri + s] = P[(size_t)(n0 + 4 * ri + s) * R_ + ct1];
    } else {
#pragma unroll
      for (int ri = 0; ri < 4; ++ri)
#pragma unroll
        for (int s = 0; s < 4; ++s)
          ld[4 * ri + s] = P[(size_t)(n0 + 4 * (2 * ri + hb) + s) * R_ + gc0];
    }
  };

  auto do_write = [&](int n0) {
    if (tile == 1) {
#pragma unroll
      for (int ri = 0; ri < 8; ++ri) {
        u32 qw[4];
#pragma unroll
        for (int s = 0; s < 4; ++s) {
          int n = n0 + 4 * ri + s;
          float v = (n == ct1) ? 1.f : ((n > ct1) ? ld[4 * ri + s] : 0.f);
          qw[s] = pack_split(v);
        }
        *(uint4*)&VT[ct1][((ri ^ (ct1 & 7)) << 2)] = *(uint4*)qw;
      }
    } else {
#pragma unroll
      for (int ri = 0; ri < 4; ++ri) {
        int ch = 2 * ri + hb;
        u32 qw[4];
#pragma unroll
        for (int s = 0; s < 4; ++s) {
          int n = n0 + 4 * ch + s;
          float v = (n == gc0) ? 1.f : ((n > gc0) ? ld[4 * ri + s] : 0.f);
          qw[s] = pack_split(v);
        }
        *(uint4*)&VT[ct0][((ch ^ (ct0 & 7)) << 2)] = *(uint4*)qw;
      }
    }
  };

  do_load(ns);
  for (int n0 = ns; n0 < ne; n0 += 32) {
    do_write(n0);
    __syncthreads();
    if (n0 + 32 < ne) do_load(n0 + 32);  // prefetch overlaps MFMA below

    bf16x8 Ah[4], Al[4];
#pragma unroll
    for (int mt = 0; mt < 4; ++mt) {
      int row = 64 * wr + 16 * mt + l15;
      read_frag(&VT[row][0], row, 2 * q, Ah[mt], Al[mt]);
    }
#pragma unroll
    for (int nt = 0; nt < 4; ++nt) {
      int brow = bbase + 64 * wc + 16 * nt + l15;
      bf16x8 bh, bl;
      read_frag(&VT[brow][0], brow, 2 * q, bh, bl);
#pragma unroll
      for (int mt = 0; mt < 4; ++mt)
        acc[mt][nt] = mm3(Ah[mt], Al[mt], bh, bl, acc[mt][nt]);
    }
    __syncthreads();
  }

  // C/D layout: col=lane&15, row=(lane>>4)*4+reg
  float* Sp = SP + (size_t)(chunk * 16 + b) * (R_ * R_);
#pragma unroll
  for (int mt = 0; mt < 4; ++mt)
#pragma unroll
    for (int nt = 0; nt < 4; ++nt) {
      int jj = j0 + 64 * wr + 16 * mt + 4 * q;
      int kk = k0 + 64 * wc + 16 * nt + l15;
#pragma unroll
      for (int r = 0; r < 4; ++r)
        Sp[(size_t)(jj + r) * R_ + kk] = acc[mt][nt][r];
    }
}

// ---------------------------------------------------------------------------
// reduce: S = sum over 16 chunks of SP, IN PLACE into chunk-0 slot.
// ---------------------------------------------------------------------------
__global__ __launch_bounds__(256) void reduce_kernel(float* __restrict__ SP) {
  size_t idx = (size_t)blockIdx.x * 256 + threadIdx.x;  // float4 index
  float4* sp = (float4*)SP;
  float4 a = sp[idx];
#pragma unroll
  for (int c = 1; c < 16; ++c) {
    float4 v = sp[idx + (size_t)c * 262144];
    a.x += v.x; a.y += v.y; a.z += v.z; a.w += v.w;
  }
  sp[idx] = a;
}

// ---------------------------------------------------------------------------
// K2: wave-per-column backward substitution over LDS-RESIDENT triangular S.
// Block = 1 batch x 16 interleaved columns (k = jg + 16*wave), 1024 threads,
// grid 256 (1 block/CU). The upper triangle of S (rows r, cols >= 4*(r>>2))
// is packed into 133 KB of LDS as 4-row panels:
//   base[g] = 1024g - 8g(g-1), rowlen[g] = 256 - 4g,
//   addr(r,c) = base[r>>2] + (r&3)*rowlen + (c - 4*(r>>2)).
// Staged once (coalesced float4), one barrier, then the R5-identical solver
// loop runs on ds_read_b128 only -- no global memory in the serial chain.
// Lanes l < r4 read earlier panels (in-bounds, finite) and multiply by w=0,
// exactly like R5's harmless reads -> bit-identical results.
// ---------------------------------------------------------------------------
__global__ __launch_bounds__(1024) void solve_kernel(const float* __restrict__ param,
                                                     const float* __restrict__ S,
                                                     u32* __restrict__ WtP) {
  extern __shared__ float tri[];   // 33280 floats = 133120 B
  const int t    = threadIdx.x;
  const int lane = t & 63;
  const int wave = t >> 6;               // 0..15
  const int b    = blockIdx.x >> 4;
  const int jg   = blockIdx.x & 15;
  const int k    = jg + 16 * wave;       // interleaved: equal work per block
  const float* __restrict__ Sb = S + (size_t)b * R_ * R_;
  const float* __restrict__ Pb = param + (size_t)b * N_ * R_;

  // rhs column (issued before staging so it overlaps)
  float4 x = *(const float4*)(Pb + (size_t)k * R_ + 4 * lane);
  {
    int c0 = 4 * lane;
    x.x = (c0     == k) ? 1.f : ((c0     < k) ? x.x : 0.f);
    x.y = (c0 + 1 == k) ? 1.f : ((c0 + 1 < k) ? x.y : 0.f);
    x.z = (c0 + 2 == k) ? 1.f : ((c0 + 2 < k) ? x.z : 0.f);
    x.w = (c0 + 3 == k) ? 1.f : ((c0 + 3 < k) ? x.w : 0.f);
  }

  // ---- stage upper-tri S into LDS (coalesced float4 reads, ~2.1 MB/block) ----
  const float4* S4 = (const float4*)Sb;
#pragma unroll
  for (int m = 0; m < 16; ++m) {
    int idx = t + 1024 * m;        // 0..16383 over the full 256x256
    int r  = idx >> 6;
    int c4 = idx & 63;
    int g  = r >> 2;
    if (c4 >= g) {
      float4 v = S4[idx];
      int rowlen = 256 - 4 * g;
      int addr = 1024 * g - 8 * g * (g - 1) + (r & 3) * rowlen + 4 * (c4 - g);
      *(float4*)&tri[addr] = v;
    }
  }
  __syncthreads();

  float4 w = make_float4(0.f, 0.f, 0.f, 0.f);
  const int k4 = k >> 2;
  int rowlen = 256 - 4 * k4;
  int base   = 1024 * k4 - 8 * k4 * (k4 - 1);

  for (int r4 = k4;; --r4) {
    const float* rb = tri + base + 4 * lane - 4 * r4;
    float4 rA0 = *(const float4*)(rb);
    float4 rA1 = *(const float4*)(rb + rowlen);
    float4 rA2 = *(const float4*)(rb + 2 * rowlen);
    float4 rA3 = *(const float4*)(rb + 3 * rowlen);

    float s0 = fmaf(rA0.x, w.x, fmaf(rA0.y, w.y, fmaf(rA0.z, w.z, rA0.w * w.w)));
    float s1 = fmaf(rA1.x, w.x, fmaf(rA1.y, w.y, fmaf(rA1.z, w.z, rA1.w * w.w)));
    float s2 = fmaf(rA2.x, w.x, fmaf(rA2.y, w.y, fmaf(rA2.z, w.z, rA2.w * w.w)));
    float s3 = fmaf(rA3.x, w.x, fmaf(rA3.y, w.y, fmaf(rA3.z, w.z, rA3.w * w.w)));
#pragma unroll
    for (int m = 1; m < 64; m <<= 1) {
      s0 += __shfl_xor(s0, m);
      s1 += __shfl_xor(s1, m);
      s2 += __shfl_xor(s2, m);
      s3 += __shfl_xor(s3, m);
    }
    // owner-lane correction chain (rows 4r4+3 .. 4r4); on lane r4 the rAj
    // float4 holds S[4r4+j][4r4..4r4+3].
    float w3 = 2.f * __builtin_amdgcn_rcpf(rA3.w) * (x.w - s3);
    float s2c = fmaf(rA2.w, w3, s2);
    float w2 = 2.f * __builtin_amdgcn_rcpf(rA2.z) * (x.z - s2c);
    float s1c = fmaf(rA1.z, w2, fmaf(rA1.w, w3, s1));
    float w1 = 2.f * __builtin_amdgcn_rcpf(rA1.y) * (x.y - s1c);
    float s0c = fmaf(rA0.y, w1, fmaf(rA0.z, w2, fmaf(rA0.w, w3, s0)));
    float w0 = 2.f * __builtin_amdgcn_rcpf(rA0.x) * (x.x - s0c);
    if (lane == r4) { w.w = w3; w.z = w2; w.y = w1; w.x = w0; }

    if (r4 == 0) break;
    rowlen += 4;            // rowlen[r4-1]
    base   -= 4 * rowlen;   // base[r4-1] = base[r4] - 4*rowlen[r4-1]
  }

  u32 pw[4] = { pack_split(w.x), pack_split(w.y), pack_split(w.z), pack_split(w.w) };
  *(uint4*)(WtP + ((size_t)b * R_ + k) * R_ + 4 * lane) = *(uint4*)pw;
}

// ---------------------------------------------------------------------------
// K3: Q = E - V @ W via MFMA. grid (32, 2, 16), block 256 (4 waves 2x2).
// 128x128 output tile, BK=32. LDS VA/WB XOR-swizzled packed u32.
// ---------------------------------------------------------------------------
__global__ __launch_bounds__(256) void final_kernel(const float* __restrict__ param,
                                                    const u32* __restrict__ WtP,
                                                    float* __restrict__ Q) {
  const int b  = blockIdx.z;
  const int n0 = blockIdx.x * 128;
  const int k0 = blockIdx.y * 128;
  const float* __restrict__ Pb = param + (size_t)b * N_ * R_;
  const u32* __restrict__ Wb = WtP + (size_t)b * R_ * R_;
  float* __restrict__ Qb = Q + (size_t)b * N_ * R_;

  __shared__ u32 VA[128][32];
  __shared__ u32 WB[128][32];

  const int t = threadIdx.x;
  const int lane = t & 63, wv = t >> 6;
  const int wr = wv >> 1, wc = wv & 1;
  const int l15 = lane & 15, q = lane >> 4;
  const int row8 = t >> 3;   // 0..31
  const int c4 = t & 7;

  f32x4 acc[4][4];
#pragma unroll
  for (int i = 0; i < 4; ++i)
#pragma unroll
    for (int j = 0; j < 4; ++j) acc[i][j] = (f32x4){0.f, 0.f, 0.f, 0.f};

  const int jend = k0 + 128;
  for (int jb = 0; jb < jend; jb += 32) {
#pragma unroll
    for (int pi = 0; pi < 4; ++pi) {
      int row = row8 + 32 * pi;
      int n = n0 + row;
      int gj = jb + 4 * c4;
      float4 v = *(const float4*)&Pb[(size_t)n * R_ + gj];
      u32 qw[4];
      qw[0] = pack_split((n == gj    ) ? 1.f : ((n > gj    ) ? v.x : 0.f));
      qw[1] = pack_split((n == gj + 1) ? 1.f : ((n > gj + 1) ? v.y : 0.f));
      qw[2] = pack_split((n == gj + 2) ? 1.f : ((n > gj + 2) ? v.z : 0.f));
      qw[3] = pack_split((n == gj + 3) ? 1.f : ((n > gj + 3) ? v.w : 0.f));
      *(uint4*)&VA[row][((c4 ^ (row & 7)) << 2)] = *(uint4*)qw;
      uint4 wq = *(const uint4*)&Wb[(size_t)(k0 + row) * R_ + gj];
      *(uint4*)&WB[row][((c4 ^ (row & 7)) << 2)] = wq;
    }
    __syncthreads();

    bf16x8 Ah[4], Al[4];
#pragma unroll
    for (int mt = 0; mt < 4; ++mt) {
      int row = 64 * wr + 16 * mt + l15;
      read_frag(&VA[row][0], row, 2 * q, Ah[mt], Al[mt]);
    }
#pragma unroll
    for (int nt = 0; nt < 4; ++nt) {
      int krow = 64 * wc + 16 * nt + l15;
      bf16x8 bh, bl;
      read_frag(&WB[krow][0], krow, 2 * q, bh, bl);
#pragma unroll
      for (int mt = 0; mt < 4; ++mt)
        acc[mt][nt] = mm3(Ah[mt], Al[mt], bh, bl, acc[mt][nt]);
    }
    __syncthreads();
  }

#pragma unroll
  for (int mt = 0; mt < 4; ++mt)
#pragma unroll
    for (int nt = 0; nt < 4; ++nt) {
      int nrow = n0 + 64 * wr + 16 * mt + 4 * q;
      int kcol = k0 + 64 * wc + 16 * nt + l15;
#pragma unroll
      for (int r = 0; r < 4; ++r) {
        float val = ((nrow + r == kcol) ? 1.f : 0.f) - acc[mt][nt][r];
        Qb[(size_t)(nrow + r) * R_ + kcol] = val;
      }
    }
}

extern "C" void kernel_launch(void* const* d_in, const int* in_sizes, int n_in,
                              void* d_out, int out_size, void* d_ws, size_t ws_size,
                              hipStream_t stream) {
  const float* param = (const float*)d_in[0];
  float* Q  = (float*)d_out;
  // d_out during pipeline: SP = 16 chunks x 16 b x 256x256 fp32 = the WHOLE
  // 64 MB of d_out. reduce sums chunks 1..15 into chunk 0 in place, so
  // S = d_out base. final_kernel then overwrites all of d_out with Q.
  float* SP = Q;
  float* S  = Q;
  u32*   WtP = (u32*)d_ws;  // 4 MB packed split-bf16 W^T

  gram_kernel<<<dim3(3, 16, B_), 256, 0, stream>>>(param, SP);
  reduce_kernel<<<dim3(1024), 256, 0, stream>>>(SP);
  solve_kernel<<<dim3(256), 1024, 133120, stream>>>(param, S, WtP);
  final_kernel<<<dim3(32, 2, B_), 256, 0, stream>>>(param, WtP, Q);
}

// Round 8
// 149.259 us; speedup vs baseline: 1.3149x; 1.1174x over previous
//
#include <hip/hip_runtime.h>
#include <stdint.h>

#define B_ 16
#define N_ 4096
#define R_ 256

typedef short bf16x8 __attribute__((ext_vector_type(8)));
typedef float f32x4 __attribute__((ext_vector_type(4)));
typedef uint32_t u32;

// V[b,n,i] = (n==i) ? 1 : (n>i ? param[b,n,i] : 0)
// Pipeline: S = V^T V (split-bf16 MFMA, 3 upper 128x128 tiles, 16 n-chunk
// partials filling d_out) -> reduce (in-place into chunk 0 => S = d_out base)
// -> solve (diag(1/tau)+strictU(S)) W = Vtop^T (wave-per-column over an
// LDS-resident upper-triangular S, DPP wave-sum, W packed hi|lo bf16 into
// d_ws) -> Q = E - V W (split-bf16 MFMA).
//
// Split: fp32 x ~= hi + lo, both TRUNCATED bf16 (5 VALU ops; lo = x - hi is
// exact, trunc err ~2^-16|x|). x*y ~= xh*yh + xh*yl + xl*yh (3 MFMAs).

__device__ __forceinline__ u32 pack_split(float x) {
  u32 u = __float_as_uint(x);
  u32 h = u & 0xffff0000u;           // hi = trunc bf16
  float l = x - __uint_as_float(h);  // exact remainder
  return h | (__float_as_uint(l) >> 16);
}

// Build hi/lo bf16x8 fragments from 8 packed words (k-order preserved).
__device__ __forceinline__ void unpack8(const u32* w, bf16x8& hi, bf16x8& lo) {
  union { u32 u[4]; bf16x8 v; } H, L;
#pragma unroll
  for (int i = 0; i < 4; ++i) {
    u32 a = w[2 * i], b = w[2 * i + 1];
    H.u[i] = (a >> 16) | (b & 0xffff0000u);
    L.u[i] = (a & 0xffffu) | (b << 16);
  }
  hi = H.v; lo = L.v;
}

// Read one A/B fragment pair from a swizzled [row][32-word] LDS tile.
__device__ __forceinline__ void read_frag(const u32* rowbase, int row, int q2,
                                          bf16x8& hi, bf16x8& lo) {
  u32 w[8];
  const int s = row & 7;
  *(uint4*)&w[0] = *(const uint4*)(rowbase + (((q2    ) ^ s) << 2));
  *(uint4*)&w[4] = *(const uint4*)(rowbase + (((q2 + 1) ^ s) << 2));
  unpack8(w, hi, lo);
}

__device__ __forceinline__ f32x4 mm3(bf16x8 ah, bf16x8 al, bf16x8 bh, bf16x8 bl,
                                     f32x4 c) {
  c = __builtin_amdgcn_mfma_f32_16x16x32_bf16(al, bh, c, 0, 0, 0);
  c = __builtin_amdgcn_mfma_f32_16x16x32_bf16(ah, bl, c, 0, 0, 0);
  c = __builtin_amdgcn_mfma_f32_16x16x32_bf16(ah, bh, c, 0, 0, 0);
  return c;
}

// ---------------------------------------------------------------------------
// K1: partial Gram via MFMA. grid (3 tiles, 16 n-chunks of 256, 16 b), 256 thr.
// tile0=(0,0) tile1=(0,128) tile2=(128,128).
// ---------------------------------------------------------------------------
__global__ __launch_bounds__(256) void gram_kernel(const float* __restrict__ param,
                                                   float* __restrict__ SP) {
  const int tile = blockIdx.x, chunk = blockIdx.y, b = blockIdx.z;
  const int j0 = (tile == 2) ? 128 : 0;
  const int k0 = (tile == 0) ? 0 : 128;
  const float* __restrict__ P = param + (size_t)b * N_ * R_;

  __shared__ u32 VT[256][32];

  const int t = threadIdx.x;
  const int lane = t & 63, wv = t >> 6;
  const int wr = wv >> 1, wc = wv & 1;
  const int l15 = lane & 15, q = lane >> 4;
  const int bbase = (tile == 1) ? 128 : 0;

  f32x4 acc[4][4];
#pragma unroll
  for (int i = 0; i < 4; ++i)
#pragma unroll
    for (int j = 0; j < 4; ++j) acc[i][j] = (f32x4){0.f, 0.f, 0.f, 0.f};

  const int nb = chunk * 256;
  const int ns = (nb > k0) ? nb : k0;  // n < k0: B cols all zero
  const int ne = nb + 256;

  float ld[32];

  const int ct1 = t;
  const int ct0 = t & 127;
  const int gc0 = j0 + ct0;
  const int hb  = t >> 7;

  auto do_load = [&](int n0) {
    if (tile == 1) {
#pragma unroll
      for (int ri = 0; ri < 8; ++ri)
#pragma unroll
        for (int s = 0; s < 4; ++s)
          ld[4 * ri + s] = P[(size_t)(n0 + 4 * ri + s) * R_ + ct1];
    } else {
#pragma unroll
      for (int ri = 0; ri < 4; ++ri)
#pragma unroll
        for (int s = 0; s < 4; ++s)
          ld[4 * ri + s] = P[(size_t)(n0 + 4 * (2 * ri + hb) + s) * R_ + gc0];
    }
  };

  auto do_write = [&](int n0) {
    if (tile == 1) {
#pragma unroll
      for (int ri = 0; ri < 8; ++ri) {
        u32 qw[4];
#pragma unroll
        for (int s = 0; s < 4; ++s) {
          int n = n0 + 4 * ri + s;
          float v = (n == ct1) ? 1.f : ((n > ct1) ? ld[4 * ri + s] : 0.f);
          qw[s] = pack_split(v);
        }
        *(uint4*)&VT[ct1][((ri ^ (ct1 & 7)) << 2)] = *(uint4*)qw;
      }
    } else {
#pragma unroll
      for (int ri = 0; ri < 4; ++ri) {
        int ch = 2 * ri + hb;
        u32 qw[4];
#pragma unroll
        for (int s = 0; s < 4; ++s) {
          int n = n0 + 4 * ch + s;
          float v = (n == gc0) ? 1.f : ((n > gc0) ? ld[4 * ri + s] : 0.f);
          qw[s] = pack_split(v);
        }
        *(uint4*)&VT[ct0][((ch ^ (ct0 & 7)) << 2)] = *(uint4*)qw;
      }
    }
  };

  do_load(ns);
  for (int n0 = ns; n0 < ne; n0 += 32) {
    do_write(n0);
    __syncthreads();
    if (n0 + 32 < ne) do_load(n0 + 32);  // prefetch overlaps MFMA below

    bf16x8 Ah[4], Al[4];
#pragma unroll
    for (int mt = 0; mt < 4; ++mt) {
      int row = 64 * wr + 16 * mt + l15;
      read_frag(&VT[row][0], row, 2 * q, Ah[mt], Al[mt]);
    }
#pragma unroll
    for (int nt = 0; nt < 4; ++nt) {
      int brow = bbase + 64 * wc + 16 * nt + l15;
      bf16x8 bh, bl;
      read_frag(&VT[brow][0], brow, 2 * q, bh, bl);
#pragma unroll
      for (int mt = 0; mt < 4; ++mt)
        acc[mt][nt] = mm3(Ah[mt], Al[mt], bh, bl, acc[mt][nt]);
    }
    __syncthreads();
  }

  // C/D layout: col=lane&15, row=(lane>>4)*4+reg
  float* Sp = SP + (size_t)(chunk * 16 + b) * (R_ * R_);
#pragma unroll
  for (int mt = 0; mt < 4; ++mt)
#pragma unroll
    for (int nt = 0; nt < 4; ++nt) {
      int jj = j0 + 64 * wr + 16 * mt + 4 * q;
      int kk = k0 + 64 * wc + 16 * nt + l15;
#pragma unroll
      for (int r = 0; r < 4; ++r)
        Sp[(size_t)(jj + r) * R_ + kk] = acc[mt][nt][r];
    }
}

// ---------------------------------------------------------------------------
// reduce: S = sum over 16 chunks of SP, IN PLACE into chunk-0 slot.
// ---------------------------------------------------------------------------
__global__ __launch_bounds__(256) void reduce_kernel(float* __restrict__ SP) {
  size_t idx = (size_t)blockIdx.x * 256 + threadIdx.x;  // float4 index
  float4* sp = (float4*)SP;
  float4 a = sp[idx];
#pragma unroll
  for (int c = 1; c < 16; ++c) {
    float4 v = sp[idx + (size_t)c * 262144];
    a.x += v.x; a.y += v.y; a.z += v.z; a.w += v.w;
  }
  sp[idx] = a;
}

// DPP wave64 sum: result valid in lane 63 (canonical GCN reduction).
// row_shr:1/2/4/8 then row_bcast:15 (rows 1,3) and row_bcast:31 (rows 2,3).
#define DPP_ADD(v, ctrl, rmask)                                              \
  v += __int_as_float(__builtin_amdgcn_update_dpp(                           \
      0, __float_as_int(v), ctrl, rmask, 0xf, true))

// ---------------------------------------------------------------------------
// K2: wave-per-column backward substitution over LDS-RESIDENT triangular S.
// Block = 1 batch x 16 interleaved columns (k = jg + 16*wave), 1024 threads,
// grid 256 (1 block/CU). Upper triangle packed in 133 KB LDS (4-row panels).
// Row-sums now use DPP VALU reduction (6 v_add+dpp, 0 LDS ops) + readlane
// instead of the 24-DS-op shuffle butterfly -> no LDS-pipe contention in the
// serial chain.
// ---------------------------------------------------------------------------
__global__ __launch_bounds__(1024) void solve_kernel(const float* __restrict__ param,
                                                     const float* __restrict__ S,
                                                     u32* __restrict__ WtP) {
  extern __shared__ float tri[];   // 33280 floats = 133120 B
  const int t    = threadIdx.x;
  const int lane = t & 63;
  const int wave = t >> 6;               // 0..15
  const int b    = blockIdx.x >> 4;
  const int jg   = blockIdx.x & 15;
  const int k    = jg + 16 * wave;       // interleaved: equal work per block
  const float* __restrict__ Sb = S + (size_t)b * R_ * R_;
  const float* __restrict__ Pb = param + (size_t)b * N_ * R_;

  // rhs column (issued before staging so it overlaps)
  float4 x = *(const float4*)(Pb + (size_t)k * R_ + 4 * lane);
  {
    int c0 = 4 * lane;
    x.x = (c0     == k) ? 1.f : ((c0     < k) ? x.x : 0.f);
    x.y = (c0 + 1 == k) ? 1.f : ((c0 + 1 < k) ? x.y : 0.f);
    x.z = (c0 + 2 == k) ? 1.f : ((c0 + 2 < k) ? x.z : 0.f);
    x.w = (c0 + 3 == k) ? 1.f : ((c0 + 3 < k) ? x.w : 0.f);
  }

  // ---- stage upper-tri S into LDS (coalesced float4 reads) ----
  const float4* S4 = (const float4*)Sb;
#pragma unroll
  for (int m = 0; m < 16; ++m) {
    int idx = t + 1024 * m;        // 0..16383 over the full 256x256
    int r  = idx >> 6;
    int c4 = idx & 63;
    int g  = r >> 2;
    if (c4 >= g) {
      float4 v = S4[idx];
      int rowlen = 256 - 4 * g;
      int addr = 1024 * g - 8 * g * (g - 1) + (r & 3) * rowlen + 4 * (c4 - g);
      *(float4*)&tri[addr] = v;
    }
  }
  __syncthreads();

  float4 w = make_float4(0.f, 0.f, 0.f, 0.f);
  const int k4 = k >> 2;
  int rowlen = 256 - 4 * k4;
  int base   = 1024 * k4 - 8 * k4 * (k4 - 1);

  for (int r4 = k4;; --r4) {
    const float* rb = tri + base + 4 * lane - 4 * r4;
    float4 rA0 = *(const float4*)(rb);
    float4 rA1 = *(const float4*)(rb + rowlen);
    float4 rA2 = *(const float4*)(rb + 2 * rowlen);
    float4 rA3 = *(const float4*)(rb + 3 * rowlen);

    float s0 = fmaf(rA0.x, w.x, fmaf(rA0.y, w.y, fmaf(rA0.z, w.z, rA0.w * w.w)));
    float s1 = fmaf(rA1.x, w.x, fmaf(rA1.y, w.y, fmaf(rA1.z, w.z, rA1.w * w.w)));
    float s2 = fmaf(rA2.x, w.x, fmaf(rA2.y, w.y, fmaf(rA2.z, w.z, rA2.w * w.w)));
    float s3 = fmaf(rA3.x, w.x, fmaf(rA3.y, w.y, fmaf(rA3.z, w.z, rA3.w * w.w)));

    // DPP wave64 sums (4 independent chains, VALU-only), totals at lane 63
    DPP_ADD(s0, 0x111, 0xf); DPP_ADD(s1, 0x111, 0xf);
    DPP_ADD(s2, 0x111, 0xf); DPP_ADD(s3, 0x111, 0xf);
    DPP_ADD(s0, 0x112, 0xf); DPP_ADD(s1, 0x112, 0xf);
    DPP_ADD(s2, 0x112, 0xf); DPP_ADD(s3, 0x112, 0xf);
    DPP_ADD(s0, 0x114, 0xf); DPP_ADD(s1, 0x114, 0xf);
    DPP_ADD(s2, 0x114, 0xf); DPP_ADD(s3, 0x114, 0xf);
    DPP_ADD(s0, 0x118, 0xf); DPP_ADD(s1, 0x118, 0xf);
    DPP_ADD(s2, 0x118, 0xf); DPP_ADD(s3, 0x118, 0xf);
    DPP_ADD(s0, 0x142, 0xa); DPP_ADD(s1, 0x142, 0xa);
    DPP_ADD(s2, 0x142, 0xa); DPP_ADD(s3, 0x142, 0xa);
    DPP_ADD(s0, 0x143, 0xc); DPP_ADD(s1, 0x143, 0xc);
    DPP_ADD(s2, 0x143, 0xc); DPP_ADD(s3, 0x143, 0xc);
    s0 = __int_as_float(__builtin_amdgcn_readlane(__float_as_int(s0), 63));
    s1 = __int_as_float(__builtin_amdgcn_readlane(__float_as_int(s1), 63));
    s2 = __int_as_float(__builtin_amdgcn_readlane(__float_as_int(s2), 63));
    s3 = __int_as_float(__builtin_amdgcn_readlane(__float_as_int(s3), 63));

    // owner-lane correction chain (rows 4r4+3 .. 4r4); on lane r4 the rAj
    // float4 holds S[4r4+j][4r4..4r4+3].
    float w3 = 2.f * __builtin_amdgcn_rcpf(rA3.w) * (x.w - s3);
    float s2c = fmaf(rA2.w, w3, s2);
    float w2 = 2.f * __builtin_amdgcn_rcpf(rA2.z) * (x.z - s2c);
    float s1c = fmaf(rA1.z, w2, fmaf(rA1.w, w3, s1));
    float w1 = 2.f * __builtin_amdgcn_rcpf(rA1.y) * (x.y - s1c);
    float s0c = fmaf(rA0.y, w1, fmaf(rA0.z, w2, fmaf(rA0.w, w3, s0)));
    float w0 = 2.f * __builtin_amdgcn_rcpf(rA0.x) * (x.x - s0c);
    if (lane == r4) { w.w = w3; w.z = w2; w.y = w1; w.x = w0; }

    if (r4 == 0) break;
    rowlen += 4;            // rowlen[r4-1]
    base   -= 4 * rowlen;   // base[r4-1] = base[r4] - 4*rowlen[r4-1]
  }

  u32 pw[4] = { pack_split(w.x), pack_split(w.y), pack_split(w.z), pack_split(w.w) };
  *(uint4*)(WtP + ((size_t)b * R_ + k) * R_ + 4 * lane) = *(uint4*)pw;
}

// ---------------------------------------------------------------------------
// K3: Q = E - V @ W via MFMA. grid (32, 2, 16), block 256 (4 waves 2x2).
// 128x128 output tile, BK=32. LDS VA/WB XOR-swizzled packed u32.
// ---------------------------------------------------------------------------
__global__ __launch_bounds__(256) void final_kernel(const float* __restrict__ param,
                                                    const u32* __restrict__ WtP,
                                                    float* __restrict__ Q) {
  const int b  = blockIdx.z;
  const int n0 = blockIdx.x * 128;
  const int k0 = blockIdx.y * 128;
  const float* __restrict__ Pb = param + (size_t)b * N_ * R_;
  const u32* __restrict__ Wb = WtP + (size_t)b * R_ * R_;
  float* __restrict__ Qb = Q + (size_t)b * N_ * R_;

  __shared__ u32 VA[128][32];
  __shared__ u32 WB[128][32];

  const int t = threadIdx.x;
  const int lane = t & 63, wv = t >> 6;
  const int wr = wv >> 1, wc = wv & 1;
  const int l15 = lane & 15, q = lane >> 4;
  const int row8 = t >> 3;   // 0..31
  const int c4 = t & 7;

  f32x4 acc[4][4];
#pragma unroll
  for (int i = 0; i < 4; ++i)
#pragma unroll
    for (int j = 0; j < 4; ++j) acc[i][j] = (f32x4){0.f, 0.f, 0.f, 0.f};

  const int jend = k0 + 128;
  for (int jb = 0; jb < jend; jb += 32) {
#pragma unroll
    for (int pi = 0; pi < 4; ++pi) {
      int row = row8 + 32 * pi;
      int n = n0 + row;
      int gj = jb + 4 * c4;
      float4 v = *(const float4*)&Pb[(size_t)n * R_ + gj];
      u32 qw[4];
      qw[0] = pack_split((n == gj    ) ? 1.f : ((n > gj    ) ? v.x : 0.f));
      qw[1] = pack_split((n == gj + 1) ? 1.f : ((n > gj + 1) ? v.y : 0.f));
      qw[2] = pack_split((n == gj + 2) ? 1.f : ((n > gj + 2) ? v.z : 0.f));
      qw[3] = pack_split((n == gj + 3) ? 1.f : ((n > gj + 3) ? v.w : 0.f));
      *(uint4*)&VA[row][((c4 ^ (row & 7)) << 2)] = *(uint4*)qw;
      uint4 wq = *(const uint4*)&Wb[(size_t)(k0 + row) * R_ + gj];
      *(uint4*)&WB[row][((c4 ^ (row & 7)) << 2)] = wq;
    }
    __syncthreads();

    bf16x8 Ah[4], Al[4];
#pragma unroll
    for (int mt = 0; mt < 4; ++mt) {
      int row = 64 * wr + 16 * mt + l15;
      read_frag(&VA[row][0], row, 2 * q, Ah[mt], Al[mt]);
    }
#pragma unroll
    for (int nt = 0; nt < 4; ++nt) {
      int krow = 64 * wc + 16 * nt + l15;
      bf16x8 bh, bl;
      read_frag(&WB[krow][0], krow, 2 * q, bh, bl);
#pragma unroll
      for (int mt = 0; mt < 4; ++mt)
        acc[mt][nt] = mm3(Ah[mt], Al[mt], bh, bl, acc[mt][nt]);
    }
    __syncthreads();
  }

#pragma unroll
  for (int mt = 0; mt < 4; ++mt)
#pragma unroll
    for (int nt = 0; nt < 4; ++nt) {
      int nrow = n0 + 64 * wr + 16 * mt + 4 * q;
      int kcol = k0 + 64 * wc + 16 * nt + l15;
#pragma unroll
      for (int r = 0; r < 4; ++r) {
        float val = ((nrow + r == kcol) ? 1.f : 0.f) - acc[mt][nt][r];
        Qb[(size_t)(nrow + r) * R_ + kcol] = val;
      }
    }
}

extern "C" void kernel_launch(void* const* d_in, const int* in_sizes, int n_in,
                              void* d_out, int out_size, void* d_ws, size_t ws_size,
                              hipStream_t stream) {
  const float* param = (const float*)d_in[0];
  float* Q  = (float*)d_out;
  // d_out during pipeline: SP = 16 chunks x 16 b x 256x256 fp32 = the WHOLE
  // 64 MB of d_out. reduce sums chunks 1..15 into chunk 0 in place, so
  // S = d_out base. final_kernel then overwrites all of d_out with Q.
  float* SP = Q;
  float* S  = Q;
  u32*   WtP = (u32*)d_ws;  // 4 MB packed split-bf16 W^T

  gram_kernel<<<dim3(3, 16, B_), 256, 0, stream>>>(param, SP);
  reduce_kernel<<<dim3(1024), 256, 0, stream>>>(SP);
  solve_kernel<<<dim3(256), 1024, 133120, stream>>>(param, S, WtP);
  final_kernel<<<dim3(32, 2, B_), 256, 0, stream>>>(param, WtP, Q);
}